// Round 1
// baseline (457.639 us; speedup 1.0000x reference)
//
#include <hip/hip_runtime.h>

// Dims fixed by the problem
// B=64, C=8, N=512, E=512, H=8, dh=64
// logits out: [B, C*N] = 262144 floats at d_out[0]
// Q3 out:     [B, C, E] = 262144 floats at d_out[262144]

typedef _Float16 f16x8 __attribute__((ext_vector_type(8)));
typedef float f32x4 __attribute__((ext_vector_type(4)));

// ---------------- colsum of Wk2 (k2sum trick: K2.sum(-1) = ne @ colsum) ----
__global__ __launch_bounds__(256) void colsum_kernel(const float* __restrict__ Wk2,
                                                     float* __restrict__ colsum) {
  int col = blockIdx.x * 256 + threadIdx.x;  // grid 2 -> 512 cols
  float s = 0.f;
  for (int e = 0; e < 512; ++e) s += Wk2[e * 512 + col];
  colsum[col] = s;
}

// ---------------- k2sum[b,n] = dot(ne[b,n,:], colsum) ----------------------
__global__ __launch_bounds__(256) void k2sum_kernel(const float* __restrict__ ne,
                                                    const float* __restrict__ colsum,
                                                    float* __restrict__ k2sum) {
  const int wave = threadIdx.x >> 6, lane = threadIdx.x & 63;
  const int row = blockIdx.x * 4 + wave;  // grid 8192 -> 32768 rows
  float s = 0.f;
#pragma unroll
  for (int i = 0; i < 8; ++i) {
    int k = i * 64 + lane;
    s += ne[(size_t)row * 512 + k] * colsum[k];
  }
#pragma unroll
  for (int off = 32; off; off >>= 1) s += __shfl_down(s, off, 64);
  if (lane == 0) k2sum[row] = s;
}

// ---------------- Q1 = [ge | sc] @ [Wqf | Wqs].T  (K=1026), + u_scalar -----
__global__ __launch_bounds__(256) void q1_kernel(
    const float* __restrict__ ge, const float* __restrict__ sc,
    const float* __restrict__ Wqf, const float* __restrict__ Wqs,
    const float* __restrict__ v, float* __restrict__ Q1,
    float* __restrict__ u_scalar) {
  const int mb = blockIdx.x, nb = blockIdx.y;  // 8 x 8 blocks of 64x64
  const int tid = threadIdx.x;
  const int ty = tid >> 4, tx = tid & 15;
  __shared__ float As[64][33];
  __shared__ float Ws[64][33];
  float acc[4][4] = {};
  for (int kt = 0; kt < 33; ++kt) {
    const int kb = kt * 32;
#pragma unroll
    for (int i = 0; i < 8; ++i) {
      int f = tid + i * 256;
      int r = f >> 5, cc = f & 31;
      int k = kb + cc;
      int m = mb * 64 + r;
      int e = nb * 64 + r;
      float a = 0.f, w = 0.f;
      if (k < 512) {
        a = ge[(m >> 3) * 512 + k];  // graph_embedding broadcast over c (m = b*8+c)
        w = Wqf[(size_t)e * 512 + k];
      } else if (k < 1026) {
        a = sc[(size_t)m * 514 + (k - 512)];
        w = Wqs[(size_t)e * 514 + (k - 512)];
      }
      As[r][cc] = a;
      Ws[r][cc] = w;
    }
    __syncthreads();
#pragma unroll
    for (int k = 0; k < 32; ++k) {
      float av[4], bv[4];
#pragma unroll
      for (int i = 0; i < 4; ++i) av[i] = As[ty * 4 + i][k];
#pragma unroll
      for (int j = 0; j < 4; ++j) bv[j] = Ws[tx * 4 + j][k];
#pragma unroll
      for (int i = 0; i < 4; ++i)
#pragma unroll
        for (int j = 0; j < 4; ++j) acc[i][j] += av[i] * bv[j];
    }
    __syncthreads();
  }
#pragma unroll
  for (int i = 0; i < 4; ++i) {
    int m = mb * 64 + ty * 4 + i;
    float us = 0.f;
#pragma unroll
    for (int j = 0; j < 4; ++j) {
      int e = nb * 64 + tx * 4 + j;
      float q = acc[i][j];
      Q1[(size_t)m * 512 + e] = q;
      us += tanhf(q) * v[e];
    }
    atomicAdd(&u_scalar[m], us);
  }
}

// ---------------- big GEMM: C[m,e] = sum_k A[m,k]*W[e,k], K=N=512 ----------
// MFMA f16 16x16x32, 128x128 tile, 4 waves each 64x64 (4x4 tiles).
template <typename OutT>
__global__ __launch_bounds__(256) void gemm_bt_mfma(const float* __restrict__ A,
                                                    const float* __restrict__ W,
                                                    OutT* __restrict__ C, int mblocks) {
  const int bid = blockIdx.x;
  const int mb = bid % mblocks, nb = bid / mblocks;  // mb fastest: same mb -> same XCD
  const int tid = threadIdx.x;
  const int lane = tid & 63, wave = tid >> 6;
  const int wm = (wave >> 1) * 64, wn = (wave & 1) * 64;
  const int row0 = mb * 128, col0 = nb * 128;

  __shared__ __align__(16) _Float16 As[128][72];  // pad 72 -> 2-way max on b128 reads
  __shared__ __align__(16) _Float16 Ws[128][72];

  f32x4 acc[4][4] = {};

  const int qd = (lane >> 4) * 8;  // k-offset of this lane's quad within K=32
  const int rr = lane & 15;

  for (int kt = 0; kt < 8; ++kt) {
    const int kbase = kt * 64;
#pragma unroll
    for (int i = 0; i < 8; ++i) {
      int f = tid + i * 256;  // 0..2047: 128 rows x 16 float4 chunks
      int r = f >> 4, c4 = (f & 15) * 4;
      float4 av = *(const float4*)(A + (size_t)(row0 + r) * 512 + kbase + c4);
      As[r][c4 + 0] = (_Float16)av.x;
      As[r][c4 + 1] = (_Float16)av.y;
      As[r][c4 + 2] = (_Float16)av.z;
      As[r][c4 + 3] = (_Float16)av.w;
      float4 wv = *(const float4*)(W + (size_t)(col0 + r) * 512 + kbase + c4);
      Ws[r][c4 + 0] = (_Float16)wv.x;
      Ws[r][c4 + 1] = (_Float16)wv.y;
      Ws[r][c4 + 2] = (_Float16)wv.z;
      Ws[r][c4 + 3] = (_Float16)wv.w;
    }
    __syncthreads();
#pragma unroll
    for (int k0 = 0; k0 < 64; k0 += 32) {
      f16x8 af[4], bfr[4];
#pragma unroll
      for (int mi = 0; mi < 4; ++mi)
        af[mi] = *(const f16x8*)&As[wm + mi * 16 + rr][k0 + qd];
#pragma unroll
      for (int ni = 0; ni < 4; ++ni)
        bfr[ni] = *(const f16x8*)&Ws[wn + ni * 16 + rr][k0 + qd];
#pragma unroll
      for (int mi = 0; mi < 4; ++mi)
#pragma unroll
        for (int ni = 0; ni < 4; ++ni)
          acc[mi][ni] =
              __builtin_amdgcn_mfma_f32_16x16x32_f16(af[mi], bfr[ni], acc[mi][ni], 0, 0, 0);
    }
    __syncthreads();
  }

  // C/D layout: col = lane&15, row = (lane>>4)*4 + reg
  const int col = lane & 15, rq = (lane >> 4) * 4;
#pragma unroll
  for (int mi = 0; mi < 4; ++mi)
#pragma unroll
    for (int ni = 0; ni < 4; ++ni)
#pragma unroll
      for (int r = 0; r < 4; ++r) {
        int m = row0 + wm + mi * 16 + rq + r;
        int e = col0 + wn + ni * 16 + col;
        C[(size_t)m * 512 + e] = (OutT)acc[mi][ni][r];
      }
}

// ---------------- attention: one block per (b,c) ---------------------------
__global__ __launch_bounds__(256) void attn_kernel(
    const float* __restrict__ Q1, const _Float16* __restrict__ K1,
    const _Float16* __restrict__ V, const int* __restrict__ mask,
    float* __restrict__ heads) {
  const int bid = blockIdx.x;          // 512
  const int b = bid & 63, c = bid >> 6;  // bid%8 == b%8 -> same-b blocks share XCD L2
  const int bc = b * 8 + c;
  const int tid = threadIdx.x;
  const int wave = tid >> 6, lane = tid & 63;

  __shared__ float att[8][512];                     // scores then attn, 16 KB
  __shared__ __align__(16) _Float16 kt[32][520];    // K/V tile, padded

  const int h = tid >> 5, nl = tid & 31;
  float qreg[64];
  {
    const float* qp = Q1 + (size_t)bc * 512 + h * 64;
#pragma unroll
    for (int d = 0; d < 64; ++d) qreg[d] = qp[d];
  }

  const _Float16* Kb = K1 + (size_t)b * 262144;
#pragma unroll 1
  for (int t = 0; t < 16; ++t) {
#pragma unroll
    for (int i = 0; i < 8; ++i) {
      int f = tid + i * 256;
      int r = f >> 6, ch = f & 63;
      *(uint4*)&kt[r][ch * 8] = *(const uint4*)(Kb + (size_t)(t * 32 + r) * 512 + ch * 8);
    }
    __syncthreads();
    float s = 0.f;
#pragma unroll
    for (int cc = 0; cc < 8; ++cc) {
      const _Float16* kp = &kt[nl][h * 64 + cc * 8];
#pragma unroll
      for (int j = 0; j < 8; ++j) s += qreg[cc * 8 + j] * (float)kp[j];
    }
    att[h][t * 32 + nl] = s;
    __syncthreads();
  }

  // softmax: wave w owns rows h=w and h=w+4 (written masked+scaled, normalized)
  for (int hh = wave; hh < 8; hh += 4) {
    float sv[8];
    float mx = -3e38f;
#pragma unroll
    for (int i = 0; i < 8; ++i) {
      int n = i * 64 + lane;
      float x = mask[(size_t)bc * 512 + n] ? -1e9f : att[hh][n] * 0.125f;
      sv[i] = x;
      mx = fmaxf(mx, x);
    }
#pragma unroll
    for (int off = 32; off; off >>= 1) mx = fmaxf(mx, __shfl_xor(mx, off, 64));
    float sum = 0.f;
#pragma unroll
    for (int i = 0; i < 8; ++i) {
      sv[i] = __expf(sv[i] - mx);
      sum += sv[i];
    }
#pragma unroll
    for (int off = 32; off; off >>= 1) sum += __shfl_xor(sum, off, 64);
    float inv = 1.f / sum;
#pragma unroll
    for (int i = 0; i < 8; ++i) att[hh][i * 64 + lane] = sv[i] * inv;
  }
  __syncthreads();

  // heads[e] = sum_n attn[h(e),n] * V[b,n,e]; thread owns e0, e0+1
  const int e0 = tid * 2;
  const int he = e0 >> 6;
  float a0 = 0.f, a1 = 0.f;
  const _Float16* Vb = V + (size_t)b * 262144;
#pragma unroll 1
  for (int t = 0; t < 16; ++t) {
#pragma unroll
    for (int i = 0; i < 8; ++i) {
      int f = tid + i * 256;
      int r = f >> 6, ch = f & 63;
      *(uint4*)&kt[r][ch * 8] = *(const uint4*)(Vb + (size_t)(t * 32 + r) * 512 + ch * 8);
    }
    __syncthreads();
#pragma unroll
    for (int n = 0; n < 32; ++n) {
      float at = att[he][t * 32 + n];
      a0 += at * (float)kt[n][e0];
      a1 += at * (float)kt[n][e0 + 1];
    }
    __syncthreads();
  }
  heads[(size_t)bc * 512 + e0] = a0;
  heads[(size_t)bc * 512 + e0 + 1] = a1;
}

// ---------------- logits ---------------------------------------------------
__global__ __launch_bounds__(256) void logits_kernel(const float* __restrict__ u,
                                                     const float* __restrict__ k2s,
                                                     const int* __restrict__ mask,
                                                     float* __restrict__ out) {
  int idx = blockIdx.x * 256 + threadIdx.x;  // grid 1024 -> 262144
  int bc = idx >> 9, n = idx & 511, b = bc >> 3;
  float r = mask[idx] ? -1e9f
                      : 10.f * tanhf(u[bc] * k2s[b * 512 + n] * 0.04419417382415922f);
  out[idx] = r;
}

extern "C" void kernel_launch(void* const* d_in, const int* in_sizes, int n_in,
                              void* d_out, int out_size, void* d_ws, size_t ws_size,
                              hipStream_t stream) {
  const float* ne = (const float*)d_in[0];    // [64,512,512]
  const float* ge = (const float*)d_in[1];    // [64,512]
  const float* sc = (const float*)d_in[2];    // [64,8,1,514]
  const int* mask = (const int*)d_in[3];      // [64,8,1,512] bool->int
  const float* Wk1 = (const float*)d_in[4];
  const float* Wv = (const float*)d_in[5];
  const float* Wk2 = (const float*)d_in[6];
  const float* Wqf = (const float*)d_in[7];
  const float* Wout = (const float*)d_in[8];
  const float* Wqs = (const float*)d_in[9];   // [512,514]
  const float* v = (const float*)d_in[10];    // [512]

  float* logits = (float*)d_out;              // [512*512]
  float* q3 = (float*)d_out + 262144;         // [512*512]

  char* ws = (char*)d_ws;
  _Float16* K1 = (_Float16*)(ws + 0);             // 33,554,432 B
  _Float16* V = (_Float16*)(ws + 33554432);       // 33,554,432 B
  float* Q1 = (float*)(ws + 67108864);            // 1,048,576 B
  float* heads = (float*)(ws + 68157440);         // 1,048,576 B
  float* k2sum = (float*)(ws + 69206016);         // 131,072 B
  float* colsum = (float*)(ws + 69337088);        // 2,048 B
  float* uscal = (float*)(ws + 69339136);         // 2,048 B

  hipMemsetAsync(uscal, 0, 2048, stream);
  colsum_kernel<<<2, 256, 0, stream>>>(Wk2, colsum);
  q1_kernel<<<dim3(8, 8), 256, 0, stream>>>(ge, sc, Wqf, Wqs, v, Q1, uscal);
  gemm_bt_mfma<_Float16><<<1024, 256, 0, stream>>>(ne, Wk1, K1, 256);
  gemm_bt_mfma<_Float16><<<1024, 256, 0, stream>>>(ne, Wv, V, 256);
  k2sum_kernel<<<8192, 256, 0, stream>>>(ne, colsum, k2sum);
  attn_kernel<<<512, 256, 0, stream>>>(Q1, K1, V, mask, heads);
  gemm_bt_mfma<float><<<16, 256, 0, stream>>>(heads, Wout, q3, 4);
  logits_kernel<<<1024, 256, 0, stream>>>(uscal, k2sum, mask, logits);
}

// Round 2
// 292.536 us; speedup vs baseline: 1.5644x; 1.5644x over previous
//
#include <hip/hip_runtime.h>

// Dims fixed by the problem
// B=64, C=8, N=512, E=512, H=8, dh=64
// logits out: [B, C*N] = 262144 floats at d_out[0]
// Q3 out:     [B, C, E] = 262144 floats at d_out[262144]

typedef _Float16 f16x8 __attribute__((ext_vector_type(8)));
typedef float f32x4 __attribute__((ext_vector_type(4)));

// ---------------- colsum of Wk2 (k2sum trick: K2.sum(-1) = ne @ colsum) ----
// 16 blocks x 256 threads: block owns 32 cols, 8 row-groups of 64 rows each.
__global__ __launch_bounds__(256) void colsum_kernel(const float* __restrict__ Wk2,
                                                     float* __restrict__ colsum) {
  const int tx = threadIdx.x & 31, ty = threadIdx.x >> 5;  // 32 cols x 8 groups
  const int col = blockIdx.x * 32 + tx;
  float s = 0.f;
#pragma unroll 4
  for (int e = ty * 64; e < ty * 64 + 64; ++e) s += Wk2[e * 512 + col];
  __shared__ float red[8][32];
  red[ty][tx] = s;
  __syncthreads();
  if (ty == 0) {
    float t = 0.f;
#pragma unroll
    for (int g = 0; g < 8; ++g) t += red[g][tx];
    colsum[col] = t;
  }
}

// ---------------- k2sum[b,n] = dot(ne[b,n,:], colsum) ----------------------
__global__ __launch_bounds__(256) void k2sum_kernel(const float* __restrict__ ne,
                                                    const float* __restrict__ colsum,
                                                    float* __restrict__ k2sum) {
  const int wave = threadIdx.x >> 6, lane = threadIdx.x & 63;
  const int row = blockIdx.x * 4 + wave;  // grid 8192 -> 32768 rows
  float s = 0.f;
#pragma unroll
  for (int i = 0; i < 8; ++i) {
    int k = i * 64 + lane;
    s += ne[(size_t)row * 512 + k] * colsum[k];
  }
#pragma unroll
  for (int off = 32; off; off >>= 1) s += __shfl_down(s, off, 64);
  if (lane == 0) k2sum[row] = s;
}

// ---------------- Q1 = [ge | sc] @ [Wqf | Wqs].T  (K=1026) -----------------
// K-split MFMA: grid (8 mb, 8 nb, 4 ks). Each block: 64x64 tile over a
// 288-wide K chunk (9 k-tiles of 32), f16 MFMA, fp32 atomicAdd into Q1.
// Q1 must be zeroed before launch (memset in kernel_launch).
__global__ __launch_bounds__(256) void q1_mfma_kernel(
    const float* __restrict__ ge, const float* __restrict__ sc,
    const float* __restrict__ Wqf, const float* __restrict__ Wqs,
    float* __restrict__ Q1) {
  const int mb = blockIdx.x, nb = blockIdx.y, ks = blockIdx.z;
  const int tid = threadIdx.x;
  const int lane = tid & 63, wave = tid >> 6;
  const int wm = (wave >> 1) * 32, wn = (wave & 1) * 32;  // 32x32 quadrant/wave

  __shared__ __align__(16) _Float16 As[64][40];
  __shared__ __align__(16) _Float16 Ws[64][40];

  f32x4 acc[2][2] = {};
  const int qd = (lane >> 4) * 8, rr = lane & 15;

  for (int kt = 0; kt < 9; ++kt) {
    const int kb = ks * 288 + kt * 32;
    // stage 64 rows x 32 k of A and W (element-wise, handles the 512/1026
    // concat boundary and zero-pad past 1026)
#pragma unroll
    for (int f0 = 0; f0 < 2; ++f0) {
      int f = tid + f0 * 256;          // 0..511
      int r = f >> 3, c4 = (f & 7) * 4;
      int m = mb * 64 + r;             // m = b*8 + c
      int e = nb * 64 + r;
#pragma unroll
      for (int j = 0; j < 4; ++j) {
        int k = kb + c4 + j;
        float a = 0.f, w = 0.f;
        if (k < 512) {
          a = ge[(m >> 3) * 512 + k];
          w = Wqf[(size_t)e * 512 + k];
        } else if (k < 1026) {
          a = sc[(size_t)m * 514 + (k - 512)];
          w = Wqs[(size_t)e * 514 + (k - 512)];
        }
        As[r][c4 + j] = (_Float16)a;
        Ws[r][c4 + j] = (_Float16)w;
      }
    }
    __syncthreads();
    f16x8 af[2], bfr[2];
#pragma unroll
    for (int mi = 0; mi < 2; ++mi) af[mi] = *(const f16x8*)&As[wm + mi * 16 + rr][qd];
#pragma unroll
    for (int ni = 0; ni < 2; ++ni) bfr[ni] = *(const f16x8*)&Ws[wn + ni * 16 + rr][qd];
#pragma unroll
    for (int mi = 0; mi < 2; ++mi)
#pragma unroll
      for (int ni = 0; ni < 2; ++ni)
        acc[mi][ni] =
            __builtin_amdgcn_mfma_f32_16x16x32_f16(af[mi], bfr[ni], acc[mi][ni], 0, 0, 0);
    __syncthreads();
  }

  // C/D layout: col = lane&15, row = (lane>>4)*4 + reg
  const int col = lane & 15, rq = (lane >> 4) * 4;
#pragma unroll
  for (int mi = 0; mi < 2; ++mi)
#pragma unroll
    for (int ni = 0; ni < 2; ++ni)
#pragma unroll
      for (int r = 0; r < 4; ++r) {
        int m = mb * 64 + wm + mi * 16 + rq + r;
        int e = nb * 64 + wn + ni * 16 + col;
        atomicAdd(&Q1[(size_t)m * 512 + e], acc[mi][ni][r]);
      }
}

// ---------------- big GEMM: C[m,e] = sum_k A[m,k]*W[e,k], K=N=512 ----------
// MFMA f16 16x16x32, 128x128 tile, 4 waves each 64x64 (4x4 tiles).
template <typename OutT>
__global__ __launch_bounds__(256) void gemm_bt_mfma(const float* __restrict__ A,
                                                    const float* __restrict__ W,
                                                    OutT* __restrict__ C, int mblocks) {
  const int bid = blockIdx.x;
  const int mb = bid % mblocks, nb = bid / mblocks;  // mb fastest: same mb -> same XCD
  const int tid = threadIdx.x;
  const int lane = tid & 63, wave = tid >> 6;
  const int wm = (wave >> 1) * 64, wn = (wave & 1) * 64;
  const int row0 = mb * 128, col0 = nb * 128;

  __shared__ __align__(16) _Float16 As[128][72];
  __shared__ __align__(16) _Float16 Ws[128][72];

  f32x4 acc[4][4] = {};

  const int qd = (lane >> 4) * 8;
  const int rr = lane & 15;

  for (int kt = 0; kt < 8; ++kt) {
    const int kbase = kt * 64;
#pragma unroll
    for (int i = 0; i < 8; ++i) {
      int f = tid + i * 256;  // 0..2047: 128 rows x 16 float4 chunks
      int r = f >> 4, c4 = (f & 15) * 4;
      float4 av = *(const float4*)(A + (size_t)(row0 + r) * 512 + kbase + c4);
      As[r][c4 + 0] = (_Float16)av.x;
      As[r][c4 + 1] = (_Float16)av.y;
      As[r][c4 + 2] = (_Float16)av.z;
      As[r][c4 + 3] = (_Float16)av.w;
      float4 wv = *(const float4*)(W + (size_t)(col0 + r) * 512 + kbase + c4);
      Ws[r][c4 + 0] = (_Float16)wv.x;
      Ws[r][c4 + 1] = (_Float16)wv.y;
      Ws[r][c4 + 2] = (_Float16)wv.z;
      Ws[r][c4 + 3] = (_Float16)wv.w;
    }
    __syncthreads();
#pragma unroll
    for (int k0 = 0; k0 < 64; k0 += 32) {
      f16x8 af[4], bfr[4];
#pragma unroll
      for (int mi = 0; mi < 4; ++mi)
        af[mi] = *(const f16x8*)&As[wm + mi * 16 + rr][k0 + qd];
#pragma unroll
      for (int ni = 0; ni < 4; ++ni)
        bfr[ni] = *(const f16x8*)&Ws[wn + ni * 16 + rr][k0 + qd];
#pragma unroll
      for (int mi = 0; mi < 4; ++mi)
#pragma unroll
        for (int ni = 0; ni < 4; ++ni)
          acc[mi][ni] =
              __builtin_amdgcn_mfma_f32_16x16x32_f16(af[mi], bfr[ni], acc[mi][ni], 0, 0, 0);
    }
    __syncthreads();
  }

  const int col = lane & 15, rq = (lane >> 4) * 4;
#pragma unroll
  for (int mi = 0; mi < 4; ++mi)
#pragma unroll
    for (int ni = 0; ni < 4; ++ni)
#pragma unroll
      for (int r = 0; r < 4; ++r) {
        int m = row0 + wm + mi * 16 + rq + r;
        int e = col0 + wn + ni * 16 + col;
        C[(size_t)m * 512 + e] = (OutT)acc[mi][ni][r];
      }
}

// ---------------- attention: one block per (b,c) ---------------------------
__global__ __launch_bounds__(256) void attn_kernel(
    const float* __restrict__ Q1, const _Float16* __restrict__ K1,
    const _Float16* __restrict__ V, const int* __restrict__ mask,
    float* __restrict__ heads) {
  const int bid = blockIdx.x;            // 512
  const int b = bid & 63, c = bid >> 6;  // bid%8 == b%8 -> same-b blocks share XCD L2
  const int bc = b * 8 + c;
  const int tid = threadIdx.x;
  const int wave = tid >> 6, lane = tid & 63;

  __shared__ float att[8][512];
  __shared__ __align__(16) _Float16 kt[32][520];

  const int h = tid >> 5, nl = tid & 31;
  float qreg[64];
  {
    const float* qp = Q1 + (size_t)bc * 512 + h * 64;
#pragma unroll
    for (int d = 0; d < 64; ++d) qreg[d] = qp[d];
  }

  const _Float16* Kb = K1 + (size_t)b * 262144;
#pragma unroll 1
  for (int t = 0; t < 16; ++t) {
#pragma unroll
    for (int i = 0; i < 8; ++i) {
      int f = tid + i * 256;
      int r = f >> 6, ch = f & 63;
      *(uint4*)&kt[r][ch * 8] = *(const uint4*)(Kb + (size_t)(t * 32 + r) * 512 + ch * 8);
    }
    __syncthreads();
    float s = 0.f;
#pragma unroll
    for (int cc = 0; cc < 8; ++cc) {
      const _Float16* kp = &kt[nl][h * 64 + cc * 8];
#pragma unroll
      for (int j = 0; j < 8; ++j) s += qreg[cc * 8 + j] * (float)kp[j];
    }
    att[h][t * 32 + nl] = s;
    __syncthreads();
  }

  for (int hh = wave; hh < 8; hh += 4) {
    float sv[8];
    float mx = -3e38f;
#pragma unroll
    for (int i = 0; i < 8; ++i) {
      int n = i * 64 + lane;
      float x = mask[(size_t)bc * 512 + n] ? -1e9f : att[hh][n] * 0.125f;
      sv[i] = x;
      mx = fmaxf(mx, x);
    }
#pragma unroll
    for (int off = 32; off; off >>= 1) mx = fmaxf(mx, __shfl_xor(mx, off, 64));
    float sum = 0.f;
#pragma unroll
    for (int i = 0; i < 8; ++i) {
      sv[i] = __expf(sv[i] - mx);
      sum += sv[i];
    }
#pragma unroll
    for (int off = 32; off; off >>= 1) sum += __shfl_xor(sum, off, 64);
    float inv = 1.f / sum;
#pragma unroll
    for (int i = 0; i < 8; ++i) att[hh][i * 64 + lane] = sv[i] * inv;
  }
  __syncthreads();

  const int e0 = tid * 2;
  const int he = e0 >> 6;
  float a0 = 0.f, a1 = 0.f;
  const _Float16* Vb = V + (size_t)b * 262144;
#pragma unroll 1
  for (int t = 0; t < 16; ++t) {
#pragma unroll
    for (int i = 0; i < 8; ++i) {
      int f = tid + i * 256;
      int r = f >> 6, ch = f & 63;
      *(uint4*)&kt[r][ch * 8] = *(const uint4*)(Vb + (size_t)(t * 32 + r) * 512 + ch * 8);
    }
    __syncthreads();
#pragma unroll
    for (int n = 0; n < 32; ++n) {
      float at = att[he][t * 32 + n];
      a0 += at * (float)kt[n][e0];
      a1 += at * (float)kt[n][e0 + 1];
    }
    __syncthreads();
  }
  heads[(size_t)bc * 512 + e0] = a0;
  heads[(size_t)bc * 512 + e0 + 1] = a1;
}

// ---------------- fused u_scalar + logits: one block per bc ----------------
__global__ __launch_bounds__(256) void logits_u_kernel(
    const float* __restrict__ Q1, const float* __restrict__ v,
    const float* __restrict__ k2s, const int* __restrict__ mask,
    float* __restrict__ out) {
  const int bc = blockIdx.x;  // 512
  const int b = bc >> 3;
  const int tid = threadIdx.x;
  const int wave = tid >> 6, lane = tid & 63;

  // u = sum_e tanh(Q1[bc,e]) * v[e]
  float p = tanhf(Q1[(size_t)bc * 512 + tid]) * v[tid] +
            tanhf(Q1[(size_t)bc * 512 + tid + 256]) * v[tid + 256];
#pragma unroll
  for (int off = 32; off; off >>= 1) p += __shfl_down(p, off, 64);
  __shared__ float red[4];
  __shared__ float su;
  if (lane == 0) red[wave] = p;
  __syncthreads();
  if (tid == 0) su = red[0] + red[1] + red[2] + red[3];
  __syncthreads();
  const float u = su;

#pragma unroll
  for (int i = 0; i < 2; ++i) {
    int n = tid + i * 256;
    int idx = bc * 512 + n;
    out[idx] = mask[idx] ? -1e9f
                         : 10.f * tanhf(u * k2s[b * 512 + n] * 0.04419417382415922f);
  }
}

extern "C" void kernel_launch(void* const* d_in, const int* in_sizes, int n_in,
                              void* d_out, int out_size, void* d_ws, size_t ws_size,
                              hipStream_t stream) {
  const float* ne = (const float*)d_in[0];    // [64,512,512]
  const float* ge = (const float*)d_in[1];    // [64,512]
  const float* sc = (const float*)d_in[2];    // [64,8,1,514]
  const int* mask = (const int*)d_in[3];      // [64,8,1,512]
  const float* Wk1 = (const float*)d_in[4];
  const float* Wv = (const float*)d_in[5];
  const float* Wk2 = (const float*)d_in[6];
  const float* Wqf = (const float*)d_in[7];
  const float* Wout = (const float*)d_in[8];
  const float* Wqs = (const float*)d_in[9];   // [512,514]
  const float* v = (const float*)d_in[10];    // [512]

  float* logits = (float*)d_out;              // [512*512]
  float* q3 = (float*)d_out + 262144;         // [512*512]

  char* ws = (char*)d_ws;
  _Float16* K1 = (_Float16*)(ws + 0);             // 33,554,432 B
  _Float16* V = (_Float16*)(ws + 33554432);       // 33,554,432 B
  float* Q1 = (float*)(ws + 67108864);            // 1,048,576 B
  float* heads = (float*)(ws + 68157440);         // 1,048,576 B
  float* k2sum = (float*)(ws + 69206016);         // 131,072 B
  float* colsum = (float*)(ws + 69337088);        // 2,048 B

  hipMemsetAsync(Q1, 0, 1048576, stream);  // q1_mfma accumulates via atomicAdd
  colsum_kernel<<<16, 256, 0, stream>>>(Wk2, colsum);
  q1_mfma_kernel<<<dim3(8, 8, 4), 256, 0, stream>>>(ge, sc, Wqf, Wqs, Q1);
  gemm_bt_mfma<_Float16><<<1024, 256, 0, stream>>>(ne, Wk1, K1, 256);
  gemm_bt_mfma<_Float16><<<1024, 256, 0, stream>>>(ne, Wv, V, 256);
  k2sum_kernel<<<8192, 256, 0, stream>>>(ne, colsum, k2sum);
  attn_kernel<<<512, 256, 0, stream>>>(Q1, K1, V, mask, heads);
  gemm_bt_mfma<float><<<16, 256, 0, stream>>>(heads, Wout, q3, 4);
  logits_u_kernel<<<512, 256, 0, stream>>>(Q1, v, k2sum, mask, logits);
}

// Round 3
// 251.251 us; speedup vs baseline: 1.8214x; 1.1643x over previous
//
#include <hip/hip_runtime.h>

// Dims fixed by the problem: B=64, C=8, N=512, E=512, H=8, dh=64
// logits out: [B, C*N] = 262144 floats at d_out[0]
// Q3 out:     [B, C, E] = 262144 floats at d_out[262144]

typedef _Float16 f16x8 __attribute__((ext_vector_type(8)));
typedef _Float16 f16x2 __attribute__((ext_vector_type(2)));
typedef float f32x4 __attribute__((ext_vector_type(4)));

__device__ __forceinline__ void async16(const void* g, void* l) {
  __builtin_amdgcn_global_load_lds(
      (const __attribute__((address_space(1))) unsigned int*)g,
      (__attribute__((address_space(3))) unsigned int*)l, 16, 0, 0);
}

// ---------------- prep: colsum(Wk2) + convert Wk1/Wv to f16 ----------------
// blocks 0..15: colsum; 16..143: Wk1->f16; 144..271: Wv->f16
__global__ __launch_bounds__(256) void prep_w(const float* __restrict__ Wk1,
                                              const float* __restrict__ Wv,
                                              const float* __restrict__ Wk2,
                                              _Float16* __restrict__ W1h,
                                              _Float16* __restrict__ W2h,
                                              float* __restrict__ colsum) {
  const int bid = blockIdx.x;
  if (bid < 16) {
    const int tx = threadIdx.x & 31, ty = threadIdx.x >> 5;
    const int col = bid * 32 + tx;
    float s = 0.f;
#pragma unroll 4
    for (int e = ty * 64; e < ty * 64 + 64; ++e) s += Wk2[e * 512 + col];
    __shared__ float red[8][32];
    red[ty][tx] = s;
    __syncthreads();
    if (ty == 0) {
      float t = 0.f;
#pragma unroll
      for (int g = 0; g < 8; ++g) t += red[g][tx];
      colsum[col] = t;
    }
  } else {
    const int cb = bid - 16;
    const float* src = (cb < 128) ? Wk1 : Wv;
    _Float16* dst = (cb < 128) ? W1h : W2h;
    const size_t off = (size_t)(cb & 127) * 2048 + threadIdx.x * 8;
    float4 a = *(const float4*)(src + off);
    float4 b = *(const float4*)(src + off + 4);
    union { _Float16 h[8]; uint4 u; } pk;
    pk.h[0] = (_Float16)a.x; pk.h[1] = (_Float16)a.y;
    pk.h[2] = (_Float16)a.z; pk.h[3] = (_Float16)a.w;
    pk.h[4] = (_Float16)b.x; pk.h[5] = (_Float16)b.y;
    pk.h[6] = (_Float16)b.z; pk.h[7] = (_Float16)b.w;
    *(uint4*)(dst + off) = pk.u;
  }
}

// ---------------- k2sum[b,n] = dot(ne[b,n,:], colsum) ----------------------
__global__ __launch_bounds__(256) void k2sum_kernel(const float* __restrict__ ne,
                                                    const float* __restrict__ colsum,
                                                    float* __restrict__ k2sum) {
  const int wave = threadIdx.x >> 6, lane = threadIdx.x & 63;
  const int row = blockIdx.x * 4 + wave;
  float s = 0.f;
#pragma unroll
  for (int i = 0; i < 8; ++i) {
    int k = i * 64 + lane;
    s += ne[(size_t)row * 512 + k] * colsum[k];
  }
#pragma unroll
  for (int off = 32; off; off >>= 1) s += __shfl_down(s, off, 64);
  if (lane == 0) k2sum[row] = s;
}

// ---------------- Q1 = [ge | sc] @ [Wqf | Wqs].T  (K=1026) -----------------
__global__ __launch_bounds__(256) void q1_mfma_kernel(
    const float* __restrict__ ge, const float* __restrict__ sc,
    const float* __restrict__ Wqf, const float* __restrict__ Wqs,
    float* __restrict__ Q1) {
  const int mb = blockIdx.x, nb = blockIdx.y, ks = blockIdx.z;
  const int tid = threadIdx.x;
  const int lane = tid & 63, wave = tid >> 6;
  const int wm = (wave >> 1) * 32, wn = (wave & 1) * 32;

  __shared__ __align__(16) _Float16 As[64][40];
  __shared__ __align__(16) _Float16 Ws[64][40];

  f32x4 acc[2][2] = {};
  const int qd = (lane >> 4) * 8, rr = lane & 15;

  for (int kt = 0; kt < 9; ++kt) {
    const int kb = ks * 288 + kt * 32;
#pragma unroll
    for (int f0 = 0; f0 < 2; ++f0) {
      int f = tid + f0 * 256;
      int r = f >> 3, c4 = (f & 7) * 4;
      int m = mb * 64 + r;
      int e = nb * 64 + r;
#pragma unroll
      for (int j = 0; j < 4; ++j) {
        int k = kb + c4 + j;
        float a = 0.f, w = 0.f;
        if (k < 512) {
          a = ge[(m >> 3) * 512 + k];
          w = Wqf[(size_t)e * 512 + k];
        } else if (k < 1026) {
          a = sc[(size_t)m * 514 + (k - 512)];
          w = Wqs[(size_t)e * 514 + (k - 512)];
        }
        As[r][c4 + j] = (_Float16)a;
        Ws[r][c4 + j] = (_Float16)w;
      }
    }
    __syncthreads();
    f16x8 af[2], bfr[2];
#pragma unroll
    for (int mi = 0; mi < 2; ++mi) af[mi] = *(const f16x8*)&As[wm + mi * 16 + rr][qd];
#pragma unroll
    for (int ni = 0; ni < 2; ++ni) bfr[ni] = *(const f16x8*)&Ws[wn + ni * 16 + rr][qd];
#pragma unroll
    for (int mi = 0; mi < 2; ++mi)
#pragma unroll
      for (int ni = 0; ni < 2; ++ni)
        acc[mi][ni] =
            __builtin_amdgcn_mfma_f32_16x16x32_f16(af[mi], bfr[ni], acc[mi][ni], 0, 0, 0);
    __syncthreads();
  }

  const int col = lane & 15, rq = (lane >> 4) * 4;
#pragma unroll
  for (int mi = 0; mi < 2; ++mi)
#pragma unroll
    for (int ni = 0; ni < 2; ++ni)
#pragma unroll
      for (int r = 0; r < 4; ++r) {
        int m = mb * 64 + wm + mi * 16 + rq + r;
        int e = nb * 64 + wn + ni * 16 + col;
        atomicAdd(&Q1[(size_t)m * 512 + e], acc[mi][ni][r]);
      }
}

// ---------------- fused K1+V GEMM: one A staging, two MFMA streams ---------
// A fp32 (converted in staging, padded LDS); W1/W2 f16 via global_load_lds
// with XOR-swizzled chunk slots. 128x128 tile, BK=64, K=512.
__global__ __launch_bounds__(256, 2) void gemm_kv(
    const float* __restrict__ A, const _Float16* __restrict__ W1,
    const _Float16* __restrict__ W2, _Float16* __restrict__ K1,
    _Float16* __restrict__ V) {
  const int nb = blockIdx.x;  // 0..3 fastest -> same A rows concurrent across XCDs (L3 reuse)
  const int mb = blockIdx.y;  // 0..255
  const int tid = threadIdx.x, lane = tid & 63, wave = tid >> 6;
  const int wm = (wave >> 1) * 64, wn = (wave & 1) * 64;
  const int row0 = mb * 128, col0 = nb * 128;

  __shared__ __align__(16) _Float16 As[128][72];   // padded: uniform b128 reads
  __shared__ __align__(16) _Float16 W1s[128 * 64]; // swizzled, unpadded (gload_lds)
  __shared__ __align__(16) _Float16 W2s[128 * 64];

  f32x4 acc1[4][4] = {}, acc2[4][4] = {};
  const int qd = (lane >> 4) * 8, rr = lane & 15;
  const int wlr = lane >> 3, wlc = lane & 7;  // staging row/chunk within 8-row group

  for (int kt = 0; kt < 8; ++kt) {
    const int kbase = kt * 64;
    // W staging: wave stages rows [wave*32, wave*32+32) of both W tiles
#pragma unroll
    for (int j = 0; j < 4; ++j) {
      int r = wave * 32 + j * 8 + wlr;
      int c = wlc ^ (r & 7);  // slot s holds global chunk s^(r&7)
      size_t goff = (size_t)(col0 + r) * 512 + kbase + c * 8;
      async16(W1 + goff, &W1s[(wave * 32 + j * 8) * 64]);
      async16(W2 + goff, &W2s[(wave * 32 + j * 8) * 64]);
    }
    // A staging: 1024 chunks of 8 floats -> f16
#pragma unroll
    for (int i = 0; i < 4; ++i) {
      int f = tid + i * 256;
      int r = f >> 3, c8 = (f & 7) * 8;
      const float* ap = A + (size_t)(row0 + r) * 512 + kbase + c8;
      float4 a0 = *(const float4*)ap;
      float4 a1 = *(const float4*)(ap + 4);
      union { _Float16 h[8]; uint4 u; } pk;
      pk.h[0] = (_Float16)a0.x; pk.h[1] = (_Float16)a0.y;
      pk.h[2] = (_Float16)a0.z; pk.h[3] = (_Float16)a0.w;
      pk.h[4] = (_Float16)a1.x; pk.h[5] = (_Float16)a1.y;
      pk.h[6] = (_Float16)a1.z; pk.h[7] = (_Float16)a1.w;
      *(uint4*)&As[r][c8] = pk.u;
    }
    __syncthreads();
#pragma unroll
    for (int k0 = 0; k0 < 64; k0 += 32) {
      const int q = (k0 >> 3) + (lane >> 4);
      f16x8 af[4], b1[4], b2[4];
#pragma unroll
      for (int mi = 0; mi < 4; ++mi)
        af[mi] = *(const f16x8*)&As[wm + mi * 16 + rr][k0 + qd];
#pragma unroll
      for (int ni = 0; ni < 4; ++ni) {
        int rw = wn + ni * 16 + rr;
        int slot = q ^ (rw & 7);
        b1[ni] = *(const f16x8*)&W1s[rw * 64 + slot * 8];
        b2[ni] = *(const f16x8*)&W2s[rw * 64 + slot * 8];
      }
#pragma unroll
      for (int mi = 0; mi < 4; ++mi)
#pragma unroll
        for (int ni = 0; ni < 4; ++ni) {
          acc1[mi][ni] =
              __builtin_amdgcn_mfma_f32_16x16x32_f16(af[mi], b1[ni], acc1[mi][ni], 0, 0, 0);
          acc2[mi][ni] =
              __builtin_amdgcn_mfma_f32_16x16x32_f16(af[mi], b2[ni], acc2[mi][ni], 0, 0, 0);
        }
    }
    __syncthreads();
  }

  const int col = lane & 15, rq = (lane >> 4) * 4;
#pragma unroll
  for (int mi = 0; mi < 4; ++mi)
#pragma unroll
    for (int ni = 0; ni < 4; ++ni)
#pragma unroll
      for (int r = 0; r < 4; ++r) {
        size_t m = row0 + wm + mi * 16 + rq + r;
        size_t e = col0 + wn + ni * 16 + col;
        K1[m * 512 + e] = (_Float16)acc1[mi][ni][r];
        V[m * 512 + e] = (_Float16)acc2[mi][ni][r];
      }
}

// ---------------- attention: one block per (b,c), MFMA QK^T ----------------
__global__ __launch_bounds__(256) void attn_kernel(
    const float* __restrict__ Q1, const _Float16* __restrict__ K1,
    const _Float16* __restrict__ V, const int* __restrict__ mask,
    float* __restrict__ heads) {
  const int bid = blockIdx.x;            // 512
  const int b = bid & 63, c = bid >> 6;  // same-b blocks share XCD L2
  const int bc = b * 8 + c;
  const int tid = threadIdx.x;
  const int wave = tid >> 6, lane = tid & 63;
  const int m = lane & 15, q = lane >> 4;

  __shared__ float att[8][512];                  // 16 KB
  __shared__ __align__(16) _Float16 kt[64 * 512]; // 64 KB, reused QK(64r)/PV(32r)

  // A-operand fragments: Qexp[h,e] = Q1[bc,e] when e in head h else 0.
  // kstep s covers e=[32s,32s+32); lane row m nonzero only at s=2m, 2m+1.
  f16x8 aflo = {}, afhi = {};
  if (m < 8) {
    const float* qp = Q1 + (size_t)bc * 512 + m * 64 + q * 8;
    float4 l0 = *(const float4*)qp, l1 = *(const float4*)(qp + 4);
    float4 h0 = *(const float4*)(qp + 32), h1 = *(const float4*)(qp + 36);
    aflo[0] = (_Float16)l0.x; aflo[1] = (_Float16)l0.y;
    aflo[2] = (_Float16)l0.z; aflo[3] = (_Float16)l0.w;
    aflo[4] = (_Float16)l1.x; aflo[5] = (_Float16)l1.y;
    aflo[6] = (_Float16)l1.z; aflo[7] = (_Float16)l1.w;
    afhi[0] = (_Float16)h0.x; afhi[1] = (_Float16)h0.y;
    afhi[2] = (_Float16)h0.z; afhi[3] = (_Float16)h0.w;
    afhi[4] = (_Float16)h1.x; afhi[5] = (_Float16)h1.y;
    afhi[6] = (_Float16)h1.z; afhi[7] = (_Float16)h1.w;
  }
  f16x8 afr[16];
#pragma unroll
  for (int s = 0; s < 16; ++s) {
    f16x8 z = {};
    afr[s] = (s == 2 * m) ? aflo : ((s == 2 * m + 1) ? afhi : z);
  }

  const _Float16* Kb = K1 + (size_t)b * 262144;
  // ---- QK^T: 8 tiles of 64 K-rows; wave w computes n-16-tile w ----
  for (int t = 0; t < 8; ++t) {
#pragma unroll
    for (int j = 0; j < 16; ++j) {
      int n = wave * 16 + j;
      int cg = (lane & 0x38) | ((lane ^ n) & 7);  // lane slot <- swizzled chunk
      async16(Kb + (size_t)(t * 64 + n) * 512 + cg * 8, &kt[n * 512]);
    }
    __syncthreads();
    const int nl = wave * 16 + m;
    f32x4 acc = {};
#pragma unroll
    for (int s = 0; s < 16; ++s) {
      int cc = s * 4 + q;
      int slot = (cc & 0x38) | ((cc ^ nl) & 7);
      f16x8 bf = *(const f16x8*)&kt[nl * 512 + slot * 8];
      acc = __builtin_amdgcn_mfma_f32_16x16x32_f16(afr[s], bf, acc, 0, 0, 0);
    }
#pragma unroll
    for (int r = 0; r < 4; ++r) {
      int h = q * 4 + r;  // C row = h
      if (h < 8) att[h][t * 64 + wave * 16 + m] = acc[r];
    }
    __syncthreads();
  }

  // ---- masked softmax per (h) row: wave w owns rows w and w+4 ----
  for (int hh = wave; hh < 8; hh += 4) {
    float sv[8];
    float mx = -3e38f;
#pragma unroll
    for (int i = 0; i < 8; ++i) {
      int n = i * 64 + lane;
      float x = mask[(size_t)bc * 512 + n] ? -1e9f : att[hh][n] * 0.125f;
      sv[i] = x;
      mx = fmaxf(mx, x);
    }
#pragma unroll
    for (int off = 32; off; off >>= 1) mx = fmaxf(mx, __shfl_xor(mx, off, 64));
    float sum = 0.f;
#pragma unroll
    for (int i = 0; i < 8; ++i) {
      sv[i] = __expf(sv[i] - mx);
      sum += sv[i];
    }
#pragma unroll
    for (int off = 32; off; off >>= 1) sum += __shfl_xor(sum, off, 64);
    float inv = 1.f / sum;
#pragma unroll
    for (int i = 0; i < 8; ++i) att[hh][i * 64 + lane] = sv[i] * inv;
  }
  __syncthreads();

  // ---- PV: plain-layout 32-row tiles, f16x2 conflict-free reads ----
  const int e0 = tid * 2;
  const int he = e0 >> 6;
  float a0 = 0.f, a1 = 0.f;
  const _Float16* Vb = V + (size_t)b * 262144;
  for (int t = 0; t < 16; ++t) {
#pragma unroll
    for (int i = 0; i < 8; ++i) {
      int n = wave * 8 + i;
      async16(Vb + (size_t)(t * 32 + n) * 512 + lane * 8, &kt[n * 512]);
    }
    __syncthreads();
#pragma unroll
    for (int n = 0; n < 32; ++n) {
      float at = att[he][t * 32 + n];
      f16x2 hv = *(const f16x2*)&kt[n * 512 + e0];
      a0 += at * (float)hv[0];
      a1 += at * (float)hv[1];
    }
    __syncthreads();
  }
  heads[(size_t)bc * 512 + e0] = a0;
  heads[(size_t)bc * 512 + e0 + 1] = a1;
}

// ---------------- Q3 = heads @ Wout.T (M=512), 64x64 tiles, K-split 2 ------
__global__ __launch_bounds__(256) void gemm_out64(const float* __restrict__ A,
                                                  const float* __restrict__ W,
                                                  float* __restrict__ C) {
  const int mb = blockIdx.x, nb = blockIdx.y, ks = blockIdx.z;
  const int tid = threadIdx.x;
  const int lane = tid & 63, wave = tid >> 6;
  const int wm = (wave >> 1) * 32, wn = (wave & 1) * 32;

  __shared__ __align__(16) _Float16 As[64][40];
  __shared__ __align__(16) _Float16 Ws[64][40];

  f32x4 acc[2][2] = {};
  const int qd = (lane >> 4) * 8, rr = lane & 15;

  for (int kt = 0; kt < 8; ++kt) {
    const int kb = ks * 256 + kt * 32;
#pragma unroll
    for (int f0 = 0; f0 < 2; ++f0) {
      int f = tid + f0 * 256;
      int r = f >> 3, c4 = (f & 7) * 4;
      float4 a = *(const float4*)(A + (size_t)(mb * 64 + r) * 512 + kb + c4);
      float4 w = *(const float4*)(W + (size_t)(nb * 64 + r) * 512 + kb + c4);
      As[r][c4 + 0] = (_Float16)a.x; As[r][c4 + 1] = (_Float16)a.y;
      As[r][c4 + 2] = (_Float16)a.z; As[r][c4 + 3] = (_Float16)a.w;
      Ws[r][c4 + 0] = (_Float16)w.x; Ws[r][c4 + 1] = (_Float16)w.y;
      Ws[r][c4 + 2] = (_Float16)w.z; Ws[r][c4 + 3] = (_Float16)w.w;
    }
    __syncthreads();
    f16x8 af[2], bfr[2];
#pragma unroll
    for (int mi = 0; mi < 2; ++mi) af[mi] = *(const f16x8*)&As[wm + mi * 16 + rr][qd];
#pragma unroll
    for (int ni = 0; ni < 2; ++ni) bfr[ni] = *(const f16x8*)&Ws[wn + ni * 16 + rr][qd];
#pragma unroll
    for (int mi = 0; mi < 2; ++mi)
#pragma unroll
      for (int ni = 0; ni < 2; ++ni)
        acc[mi][ni] =
            __builtin_amdgcn_mfma_f32_16x16x32_f16(af[mi], bfr[ni], acc[mi][ni], 0, 0, 0);
    __syncthreads();
  }

  const int col = lane & 15, rq = (lane >> 4) * 4;
#pragma unroll
  for (int mi = 0; mi < 2; ++mi)
#pragma unroll
    for (int ni = 0; ni < 2; ++ni)
#pragma unroll
      for (int r = 0; r < 4; ++r) {
        int m = mb * 64 + wm + mi * 16 + rq + r;
        int e = nb * 64 + wn + ni * 16 + col;
        atomicAdd(&C[(size_t)m * 512 + e], acc[mi][ni][r]);
      }
}

// ---------------- fused u_scalar + logits ----------------------------------
__global__ __launch_bounds__(256) void logits_u_kernel(
    const float* __restrict__ Q1, const float* __restrict__ v,
    const float* __restrict__ k2s, const int* __restrict__ mask,
    float* __restrict__ out) {
  const int bc = blockIdx.x;
  const int b = bc >> 3;
  const int tid = threadIdx.x;
  const int wave = tid >> 6, lane = tid & 63;

  float p = tanhf(Q1[(size_t)bc * 512 + tid]) * v[tid] +
            tanhf(Q1[(size_t)bc * 512 + tid + 256]) * v[tid + 256];
#pragma unroll
  for (int off = 32; off; off >>= 1) p += __shfl_down(p, off, 64);
  __shared__ float red[4];
  __shared__ float su;
  if (lane == 0) red[wave] = p;
  __syncthreads();
  if (tid == 0) su = red[0] + red[1] + red[2] + red[3];
  __syncthreads();
  const float u = su;

#pragma unroll
  for (int i = 0; i < 2; ++i) {
    int n = tid + i * 256;
    int idx = bc * 512 + n;
    out[idx] = mask[idx] ? -1e9f
                         : 10.f * tanhf(u * k2s[b * 512 + n] * 0.04419417382415922f);
  }
}

extern "C" void kernel_launch(void* const* d_in, const int* in_sizes, int n_in,
                              void* d_out, int out_size, void* d_ws, size_t ws_size,
                              hipStream_t stream) {
  const float* ne = (const float*)d_in[0];
  const float* ge = (const float*)d_in[1];
  const float* sc = (const float*)d_in[2];
  const int* mask = (const int*)d_in[3];
  const float* Wk1 = (const float*)d_in[4];
  const float* Wv = (const float*)d_in[5];
  const float* Wk2 = (const float*)d_in[6];
  const float* Wqf = (const float*)d_in[7];
  const float* Wout = (const float*)d_in[8];
  const float* Wqs = (const float*)d_in[9];
  const float* v = (const float*)d_in[10];

  float* logits = (float*)d_out;
  float* q3 = (float*)d_out + 262144;

  char* ws = (char*)d_ws;
  _Float16* K1 = (_Float16*)(ws + 0);          // 33,554,432 B
  _Float16* V = (_Float16*)(ws + 33554432);    // 33,554,432 B
  float* Q1 = (float*)(ws + 67108864);         // 1,048,576 B
  float* heads = (float*)(ws + 68157440);      // 1,048,576 B
  float* k2sum = (float*)(ws + 69206016);      // 131,072 B
  float* colsum = (float*)(ws + 69337088);     // 2,048 B
  _Float16* W1h = (_Float16*)(ws + 69339136);  // 524,288 B
  _Float16* W2h = (_Float16*)(ws + 69863424);  // 524,288 B

  hipMemsetAsync(Q1, 0, 1048576, stream);
  hipMemsetAsync(q3, 0, 1048576, stream);
  prep_w<<<272, 256, 0, stream>>>(Wk1, Wv, Wk2, W1h, W2h, colsum);
  q1_mfma_kernel<<<dim3(8, 8, 4), 256, 0, stream>>>(ge, sc, Wqf, Wqs, Q1);
  gemm_kv<<<dim3(4, 256), 256, 0, stream>>>(ne, W1h, W2h, K1, V);
  k2sum_kernel<<<8192, 256, 0, stream>>>(ne, colsum, k2sum);
  attn_kernel<<<512, 256, 0, stream>>>(Q1, K1, V, mask, heads);
  gemm_out64<<<dim3(8, 8, 2), 256, 0, stream>>>(heads, Wout, q3);
  logits_u_kernel<<<512, 256, 0, stream>>>(Q1, v, k2sum, mask, logits);
}